// Round 13
// baseline (146.677 us; speedup 1.0000x reference)
//
#include <hip/hip_runtime.h>
#include <hip/hip_fp16.h>
#include <math.h>

#define NV 10475
#define NDS 2048
#define NHAND 1554
#define NHA 777
#define NCONTACT 300
#define NQ (NHAND + NDS)             // 3602 query rows
#define NVEC4 (NV / 4)               // 2618 float4 per row
#define TAIL0 (NVEC4 * 4)            // 10472
#define MASK_DW ((NV + 31) / 32)     // 328

#define THREADS 512
#define W 4                          // waves per heavy query
#define QPB 2                        // queries per block (8 waves / W)
#define SCAN_BLOCKS ((NQ + QPB - 1) / QPB)          // 1801

#define GDI_CHUNKS 25                // 25 chunks * 12 rows = 300 contact rows
#define GDI_ROWS 12
#define GDI_GROUPS ((NV + THREADS - 1) / THREADS)   // 21 col groups of 512
#define GDI_BLOCKS (GDI_CHUNKS * GDI_GROUPS)        // 525
#define MAIN_BLOCKS (SCAN_BLOCKS + GDI_BLOCKS)      // 2326

#define INIT_BITS 0x7F7F7F7F         // fill byte 0x7F: 3.39e38 as float, init for done

#define GEO_THRESH 0.3f
#define EXT_THRESH 0.02f
#define A1c 0.04f
#define A2c 0.04f
#define B1c 0.07f
#define B2c 0.06f
#define C1c 0.01f
#define C2c 0.01f
#define D1c 0.023f
#define D2c 0.02f
#define CONTACT_W 0.5f
#define INSIDE_W 0.5f
#define HAND_W 1.0f

// fp16 round-trip (RN), identical to the reference's fp16 cast
__device__ __forceinline__ float rnd(float x) {
    return __half2float(__float2half(x));
}

__device__ __forceinline__ void upd(float g, float cx, float cy, float cz,
                                    float px, float py, float pz, float& best) {
    float dx = px - cx, dy = py - cy, dz = pz - cz;
    float d2 = fmaf(dx, dx, fmaf(dy, dy, dz * dz));
    best = fminf(best, (g < GEO_THRESH) ? INFINITY : d2);
}

// ---------------------------------------------------------------------------
// Fused kernel (single compute node; preceded only by a 14 KB 0x7F fill).
//  Scan blocks [0, SCAN_BLOCKS): 2 queries/block, 4 waves per query.
//   Diagonal >= GEO_THRESH -> light: d2 = 0 stored directly (~85%).
//   Else heavy: each of 4 waves scans a quarter of the masked row (stride
//   256 float4), reduces, and combines via uint-punned atomicMin (bit-exact
//   for non-negative floats). Coords straight from verts w/ in-reg fp16 round.
//  gdi blocks [SCAN_BLOCKS, ..): pgdi[c][v] = min over 12 contact rows
//   (geodist symmetry), fully parallel.
//  Last block to finish (agent-scope election) runs the masked-mean finalize.
// ---------------------------------------------------------------------------
__global__ __launch_bounds__(THREADS, 4)
void fused_kernel(const float* __restrict__ verts,
                  const float* __restrict__ geodist,
                  const int* __restrict__ hand_idx,
                  const int* __restrict__ ds,
                  const int* __restrict__ cidx,
                  const float* __restrict__ hw,
                  unsigned int* __restrict__ hand_min_u,
                  unsigned int* __restrict__ ds_min_u,
                  float* __restrict__ pgdi,
                  int* __restrict__ done,
                  float* __restrict__ out) {
    const int tid = threadIdx.x;
    __shared__ int lflag;

    if (blockIdx.x >= SCAN_BLOCKS) {
        // ---- gdi role ----
        const int b = blockIdx.x - SCAN_BLOCKS;
        const int g = b % GDI_GROUPS;
        const int c = b / GDI_GROUPS;
        const int v = g * THREADS + tid;
        if (v < NV) {
            const int j0 = c * GDI_ROWS;
            float m = INFINITY;
            #pragma unroll
            for (int j = 0; j < GDI_ROWS; ++j)
                m = fminf(m, geodist[(size_t)cidx[j0 + j] * NV + v]);
            pgdi[(size_t)c * NV + v] = m;
        }
    } else {
        // ---- scan role ----
        const int lane = tid & 63;
        const int wave = tid >> 6;           // 0..7
        const int sub = wave & (W - 1);      // 0..3: row quarter
        const int gw = blockIdx.x * QPB + (wave >> 2);
        if (gw < NQ) {
            const bool is_ds = (gw >= NHAND);
            const int i_out = is_ds ? (gw - NHAND) : gw;
            const int q = is_ds ? ds[i_out] : hand_idx[gw];
            unsigned int* __restrict__ tgt =
                is_ds ? &ds_min_u[i_out] : &hand_min_u[gw];

            const float gqq = geodist[(size_t)q * NV + q];   // broadcast load
            if (gqq >= GEO_THRESH) {
                // light: unmasked self-pair, d2 = 0 is the min
                if (lane == 0) *tgt = 0u;    // 4 waves store same value
            } else {
                // heavy: quarter-row masked scan
                const float* __restrict__ grow = geodist + (size_t)q * NV;
                const float px = rnd(verts[3 * q + 0]);
                const float py = rnd(verts[3 * q + 1]);
                const float pz = rnd(verts[3 * q + 2]);
                const float4* __restrict__ g4p = (const float4*)grow;
                const float4* __restrict__ v4 = (const float4*)verts;

                float best = INFINITY;
                #pragma unroll 4
                for (int j = sub * 64 + lane; j < NVEC4; j += 256) {
                    const float4 g4 = g4p[j];
                    const float4 a = v4[3 * j + 0];   // x0 y0 z0 x1
                    const float4 b = v4[3 * j + 1];   // y1 z1 x2 y2
                    const float4 c = v4[3 * j + 2];   // z2 x3 y3 z3
                    upd(g4.x, rnd(a.x), rnd(a.y), rnd(a.z), px, py, pz, best);
                    upd(g4.y, rnd(a.w), rnd(b.x), rnd(b.y), px, py, pz, best);
                    upd(g4.z, rnd(b.z), rnd(b.w), rnd(c.x), px, py, pz, best);
                    upd(g4.w, rnd(c.y), rnd(c.z), rnd(c.w), px, py, pz, best);
                }
                if (sub == 0 && lane < NV - TAIL0) {   // 3 tail candidates
                    const int n = TAIL0 + lane;
                    upd(grow[n], rnd(verts[3 * n + 0]), rnd(verts[3 * n + 1]),
                        rnd(verts[3 * n + 2]), px, py, pz, best);
                }
                #pragma unroll
                for (int off = 32; off > 0; off >>= 1)
                    best = fminf(best, __shfl_down(best, off));
                if (lane == 0)
                    atomicMin(tgt, __float_as_uint(best));  // bit-exact fp min
            }
        }
    }

    // ---- last-block election ----
    __syncthreads();
    if (tid == 0) {
        __threadfence();  // L2 writeback: release all this block's stores
        const int old = __hip_atomic_fetch_add(done, 1, __ATOMIC_ACQ_REL,
                                               __HIP_MEMORY_SCOPE_AGENT);
        lflag = (old == INIT_BITS + (int)gridDim.x - 1) ? 1 : 0;
    }
    __syncthreads();
    if (!lflag) return;
    __builtin_amdgcn_fence(__ATOMIC_ACQUIRE, "agent");

    // ---- finalize (last block, 512 threads) ----
    __shared__ unsigned int imask[MASK_DW];
    __shared__ float red[THREADS / 64][12];
    const int lane = tid & 63;
    const int wave = tid >> 6;

    for (int i = tid; i < MASK_DW; i += THREADS) imask[i] = 0u;
    __syncthreads();
    for (int i = tid; i < NDS; i += THREADS) {
        const float d = sqrtf(__uint_as_float(ds_min_u[i]) + 1e-12f);
        if (!(d > EXT_THRESH)) {
            const int v = ds[i];
            atomicOr(&imask[v >> 5], 1u << (v & 31));
        }
    }
    __syncthreads();

    float acc[12];
    #pragma unroll
    for (int k = 0; k < 12; ++k) acc[k] = 0.0f;

    for (int i = tid; i < NDS; i += THREADS) {
        const float m = sqrtf(__uint_as_float(ds_min_u[i]) + 1e-12f);
        const int v = ds[i];
        const bool ins = (imask[v >> 5] >> (v & 31)) & 1u;
        if (!ins) {
            float gdi = pgdi[v];
            #pragma unroll
            for (int c = 1; c < GDI_CHUNKS; ++c)
                gdi = fminf(gdi, pgdi[(size_t)c * NV + v]);
            const float w = 1.0f / (5.0f * gdi + 1.0f);
            acc[0] += A1c * w * tanhf(m / A2c);
            acc[1] += 1.0f;
        } else {
            acc[2] += B1c * tanhf(m / B2c);
            acc[3] += 1.0f;
        }
    }
    for (int h = tid; h < NHAND; h += THREADS) {
        const float m = sqrtf(__uint_as_float(hand_min_u[h]) + 1e-12f);
        const int v = hand_idx[h];
        const bool ins = (imask[v >> 5] >> (v & 31)) & 1u;
        const float w = -0.1f * hw[h] + 1.0f;
        const float o = w * C1c * tanhf(m / C2c);
        const float ii = D1c * tanhf(m / D2c);
        if (h < NHA) {
            if (!ins) { acc[4] += o;  acc[5] += 1.0f; }
            else      { acc[8] += ii; acc[9] += 1.0f; }
        } else {
            if (!ins) { acc[6]  += o;  acc[7]  += 1.0f; }
            else      { acc[10] += ii; acc[11] += 1.0f; }
        }
    }

    #pragma unroll
    for (int k = 0; k < 12; ++k) {
        float v = acc[k];
        #pragma unroll
        for (int off = 32; off > 0; off >>= 1)
            v += __shfl_down(v, off);
        acc[k] = v;
    }
    if (lane == 0) {
        #pragma unroll
        for (int k = 0; k < 12; ++k) red[wave][k] = acc[k];
    }
    __syncthreads();
    if (tid == 0) {
        float t[12];
        #pragma unroll
        for (int k = 0; k < 12; ++k) {
            float s = red[0][k];
            #pragma unroll
            for (int w = 1; w < THREADS / 64; ++w) s += red[w][k];
            t[k] = s;
        }
        const float contactloss = CONTACT_W * (t[0] / fmaxf(t[1], 1.0f));
        const float insideloss  = INSIDE_W  * (t[2] / fmaxf(t[3], 1.0f));
        const float hand_out = t[4] / fmaxf(t[5], 1.0f) + t[6]  / fmaxf(t[7], 1.0f);
        const float hand_in  = t[8] / fmaxf(t[9], 1.0f) + t[10] / fmaxf(t[11], 1.0f);
        out[0] = contactloss + insideloss + HAND_W * (hand_out + hand_in);
    }
}

extern "C" void kernel_launch(void* const* d_in, const int* in_sizes, int n_in,
                              void* d_out, int out_size, void* d_ws, size_t ws_size,
                              hipStream_t stream) {
    const float* vertices = (const float*)d_in[0];  // [1,NV,3]
    const float* geodist  = (const float*)d_in[1];  // [NV,NV]
    const float* hand_w   = (const float*)d_in[2];  // [NHAND]
    const int*   ds       = (const int*)d_in[3];    // [NDS]
    const int*   hand_idx = (const int*)d_in[4];    // [NHAND]
    const int*   cidx     = (const int*)d_in[5];    // [NCONTACT]
    float* out = (float*)d_out;

    // workspace: [hand_min_u | ds_min_u | done] contiguous -> one 0x7F fill,
    // then pgdi (written unconditionally, no init needed).
    char* p = (char*)d_ws;
    unsigned int* hand_min_u = (unsigned int*)p;  p += ((NHAND * 4 + 15) & ~15); // 6224
    unsigned int* ds_min_u = (unsigned int*)p;    p += ((NDS * 4 + 15) & ~15);   // 8192
    int* done = (int*)p;                          p += 16;
    const size_t fill_bytes = (size_t)((char*)p - (char*)d_ws);                  // 14432
    float* pgdi = (float*)p;                      p += (((size_t)GDI_CHUNKS * NV * 4 + 15) & ~15);

    // byte 0x7F: min-arrays become 3.39e38 (acts as +inf for d2 mins, since
    // masked-out INFINITY bits 0x7f800000 still order above it only when no
    // real candidate exists); done becomes 0x7F7F7F7F, the election base.
    hipMemsetAsync(d_ws, 0x7F, fill_bytes, stream);

    fused_kernel<<<MAIN_BLOCKS, THREADS, 0, stream>>>(
        vertices, geodist, hand_idx, ds, cidx, hand_w,
        hand_min_u, ds_min_u, pgdi, done, out);
}

// Round 14
// 32.570 us; speedup vs baseline: 4.5034x; 4.5034x over previous
//
#include <hip/hip_runtime.h>
#include <hip/hip_fp16.h>
#include <math.h>

#define NV 10475
#define NDS 2048
#define NHAND 1554
#define NHA 777
#define NCONTACT 300
#define NQ (NHAND + NDS)             // 3602 query rows
#define NVEC4 (NV / 4)               // 2618 float4 per row
#define TAIL0 (NVEC4 * 4)            // 10472
#define MASK_DW ((NV + 31) / 32)     // 328

#define THREADS 512
#define SCAN_BLOCKS ((NQ + 7) / 8)   // 451 blocks * 8 waves = 3608 >= NQ

#define GDI_CHUNKS 5                 // 5 chunks * 60 rows = 300 contact rows
#define GDI_ROWS 60
#define GDI_UNROLL 12                // 12 independent loads in flight
#define GDI_GROUPS ((NV + THREADS - 1) / THREADS)   // 21 col groups of 512
#define GDI_BLOCKS (GDI_CHUNKS * GDI_GROUPS)        // 105
#define MAIN_BLOCKS (SCAN_BLOCKS + GDI_BLOCKS)      // 556

#define GEO_THRESH 0.3f
#define EXT_THRESH 0.02f
#define A1c 0.04f
#define A2c 0.04f
#define B1c 0.07f
#define B2c 0.06f
#define C1c 0.01f
#define C2c 0.01f
#define D1c 0.023f
#define D2c 0.02f
#define CONTACT_W 0.5f
#define INSIDE_W 0.5f
#define HAND_W 1.0f

// fp16 round-trip (RN), identical to the reference's fp16 cast
__device__ __forceinline__ float rnd(float x) {
    return __half2float(__float2half(x));
}

__device__ __forceinline__ void upd(float g, float cx, float cy, float cz,
                                    float px, float py, float pz, float& best) {
    float dx = px - cx, dy = py - cy, dz = pz - cz;
    float d2 = fmaf(dx, dx, fmaf(dy, dy, dz * dz));
    best = fminf(best, (g < GEO_THRESH) ? INFINITY : d2);
}

// ---------------------------------------------------------------------------
// Main kernel (node 1 of 2).
//  Blocks [0, SCAN_BLOCKS): one wave per query. Diagonal geodist[q][q] >=
//   GEO_THRESH -> light (~85%): unmasked self-pair d2=0 is the min, write
//   sqrt(1e-12). Else heavy: full masked float4 row scan, coords straight
//   from verts (L2-resident) with in-register fp16 rounding.
//  Blocks [SCAN_BLOCKS, ..): gdi partials, 5 chunks x 60 contact rows,
//   12-deep unrolled independent loads (5 latency epochs/thread).
//   pgdi[c][v] = min_j geodist[cidx[j], v]  (exact by symmetry).
// ---------------------------------------------------------------------------
__global__ __launch_bounds__(THREADS, 4)
void main_kernel(const float* __restrict__ verts,
                 const float* __restrict__ geodist,
                 const int* __restrict__ hand_idx,
                 const int* __restrict__ ds,
                 const int* __restrict__ cidx,
                 float* __restrict__ hand_min,
                 float* __restrict__ ds_min,
                 float* __restrict__ pgdi) {
    const int tid = threadIdx.x;

    if (blockIdx.x >= SCAN_BLOCKS) {
        const int b = blockIdx.x - SCAN_BLOCKS;
        const int g = b % GDI_GROUPS;
        const int c = b / GDI_GROUPS;
        const int v = g * THREADS + tid;
        if (v < NV) {
            const int j0 = c * GDI_ROWS;
            float m = INFINITY;
            #pragma unroll 1
            for (int jo = 0; jo < GDI_ROWS; jo += GDI_UNROLL) {
                #pragma unroll
                for (int ji = 0; ji < GDI_UNROLL; ++ji) {
                    m = fminf(m, geodist[(size_t)cidx[j0 + jo + ji] * NV + v]);
                }
            }
            pgdi[(size_t)c * NV + v] = m;
        }
        return;
    }

    const int lane = tid & 63;
    const int gw = blockIdx.x * (THREADS / 64) + (tid >> 6);
    if (gw >= NQ) return;

    const bool is_ds = (gw >= NHAND);
    const int i_out = is_ds ? (gw - NHAND) : gw;
    const int q = is_ds ? ds[i_out] : hand_idx[gw];

    const float gqq = geodist[(size_t)q * NV + q];   // broadcast load
    if (gqq >= GEO_THRESH) {
        // light: self-pair unmasked, d2 = 0 is the global min
        if (lane == 0) {
            const float d = sqrtf(0.0f + 1e-12f);
            if (is_ds) ds_min[i_out] = d; else hand_min[gw] = d;
        }
        return;
    }

    // heavy: full masked row scan, coords straight from verts
    const float* __restrict__ grow = geodist + (size_t)q * NV;
    const float px = rnd(verts[3 * q + 0]);
    const float py = rnd(verts[3 * q + 1]);
    const float pz = rnd(verts[3 * q + 2]);
    const float4* __restrict__ g4p = (const float4*)grow;   // 4B-aligned OK
    const float4* __restrict__ v4 = (const float4*)verts;   // [NV*3/4] float4

    float best = INFINITY;
    #pragma unroll 4
    for (int j = lane; j < NVEC4; j += 64) {
        const float4 g4 = g4p[j];
        const float4 a = v4[3 * j + 0];   // x0 y0 z0 x1
        const float4 b = v4[3 * j + 1];   // y1 z1 x2 y2
        const float4 c = v4[3 * j + 2];   // z2 x3 y3 z3
        upd(g4.x, rnd(a.x), rnd(a.y), rnd(a.z), px, py, pz, best);
        upd(g4.y, rnd(a.w), rnd(b.x), rnd(b.y), px, py, pz, best);
        upd(g4.z, rnd(b.z), rnd(b.w), rnd(c.x), px, py, pz, best);
        upd(g4.w, rnd(c.y), rnd(c.z), rnd(c.w), px, py, pz, best);
    }
    if (lane < NV - TAIL0) {   // 3 tail candidates
        const int n = TAIL0 + lane;
        upd(grow[n], rnd(verts[3 * n + 0]), rnd(verts[3 * n + 1]),
            rnd(verts[3 * n + 2]), px, py, pz, best);
    }

    #pragma unroll
    for (int off = 32; off > 0; off >>= 1)
        best = fminf(best, __shfl_down(best, off));

    if (lane == 0) {
        const float d = sqrtf(best + 1e-12f);
        if (is_ds) ds_min[i_out] = d; else hand_min[gw] = d;
    }
}

// ---------------------------------------------------------------------------
// Finalize (node 2 of 2): single block. Inside-vertex bitmask in LDS
// (duplicate-safe scatter-max), then all masked means -> scalar loss.
// gdi = min over the 5 chunk partials at v = ds[i] (unrolled independent).
// ---------------------------------------------------------------------------
__global__ void finalize_kernel(const float* __restrict__ ds_min,
                                const float* __restrict__ pgdi,
                                const int* __restrict__ ds,
                                const float* __restrict__ hand_min,
                                const float* __restrict__ hw,
                                const int* __restrict__ hand_idx,
                                float* __restrict__ out) {
    __shared__ unsigned int imask[MASK_DW];
    const int tid = threadIdx.x;
    const int nthr = blockDim.x;

    for (int i = tid; i < MASK_DW; i += nthr) imask[i] = 0u;
    __syncthreads();
    for (int i = tid; i < NDS; i += nthr) {
        if (!(ds_min[i] > EXT_THRESH)) {
            const int v = ds[i];
            atomicOr(&imask[v >> 5], 1u << (v & 31));
        }
    }
    __syncthreads();

    float acc[12];
    #pragma unroll
    for (int k = 0; k < 12; ++k) acc[k] = 0.0f;

    for (int i = tid; i < NDS; i += nthr) {
        const float m = ds_min[i];
        const int v = ds[i];
        const bool ins = (imask[v >> 5] >> (v & 31)) & 1u;
        if (!ins) {
            float g0 = pgdi[v];
            float g1 = pgdi[(size_t)1 * NV + v];
            float g2 = pgdi[(size_t)2 * NV + v];
            float g3 = pgdi[(size_t)3 * NV + v];
            float g4 = pgdi[(size_t)4 * NV + v];
            const float gdi = fminf(fminf(fminf(g0, g1), fminf(g2, g3)), g4);
            const float w = 1.0f / (5.0f * gdi + 1.0f);
            acc[0] += A1c * w * tanhf(m / A2c);
            acc[1] += 1.0f;
        } else {
            acc[2] += B1c * tanhf(m / B2c);
            acc[3] += 1.0f;
        }
    }

    for (int h = tid; h < NHAND; h += nthr) {
        const float m = hand_min[h];
        const int v = hand_idx[h];
        const bool ins = (imask[v >> 5] >> (v & 31)) & 1u;
        const float w = -0.1f * hw[h] + 1.0f;
        const float o = w * C1c * tanhf(m / C2c);
        const float ii = D1c * tanhf(m / D2c);
        if (h < NHA) {
            if (!ins) { acc[4] += o;  acc[5] += 1.0f; }
            else      { acc[8] += ii; acc[9] += 1.0f; }
        } else {
            if (!ins) { acc[6]  += o;  acc[7]  += 1.0f; }
            else      { acc[10] += ii; acc[11] += 1.0f; }
        }
    }

    __shared__ float red[16][12];
    const int lane = tid & 63;
    const int wave = tid >> 6;
    #pragma unroll
    for (int k = 0; k < 12; ++k) {
        float v = acc[k];
        #pragma unroll
        for (int off = 32; off > 0; off >>= 1)
            v += __shfl_down(v, off);
        acc[k] = v;
    }
    if (lane == 0) {
        #pragma unroll
        for (int k = 0; k < 12; ++k) red[wave][k] = acc[k];
    }
    __syncthreads();
    if (tid == 0) {
        float t[12];
        const int nw = nthr >> 6;
        #pragma unroll
        for (int k = 0; k < 12; ++k) {
            float s = red[0][k];
            for (int w = 1; w < nw; ++w) s += red[w][k];
            t[k] = s;
        }
        const float contactloss = CONTACT_W * (t[0] / fmaxf(t[1], 1.0f));
        const float insideloss  = INSIDE_W  * (t[2] / fmaxf(t[3], 1.0f));
        const float hand_out = t[4] / fmaxf(t[5], 1.0f) + t[6]  / fmaxf(t[7], 1.0f);
        const float hand_in  = t[8] / fmaxf(t[9], 1.0f) + t[10] / fmaxf(t[11], 1.0f);
        out[0] = contactloss + insideloss + HAND_W * (hand_out + hand_in);
    }
}

extern "C" void kernel_launch(void* const* d_in, const int* in_sizes, int n_in,
                              void* d_out, int out_size, void* d_ws, size_t ws_size,
                              hipStream_t stream) {
    const float* vertices = (const float*)d_in[0];  // [1,NV,3]
    const float* geodist  = (const float*)d_in[1];  // [NV,NV]
    const float* hand_w   = (const float*)d_in[2];  // [NHAND]
    const int*   ds       = (const int*)d_in[3];    // [NDS]
    const int*   hand_idx = (const int*)d_in[4];    // [NHAND]
    const int*   cidx     = (const int*)d_in[5];    // [NCONTACT]
    float* out = (float*)d_out;

    // workspace layout (16B-aligned chunks)
    char* p = (char*)d_ws;
    float* hand_min = (float*)p;  p += ((NHAND * 4 + 15) & ~15);
    float* ds_min = (float*)p;    p += ((NDS * 4 + 15) & ~15);
    float* pgdi = (float*)p;      p += (((size_t)GDI_CHUNKS * NV * 4 + 15) & ~15);

    main_kernel<<<MAIN_BLOCKS, THREADS, 0, stream>>>(
        vertices, geodist, hand_idx, ds, cidx, hand_min, ds_min, pgdi);

    finalize_kernel<<<1, 1024, 0, stream>>>(ds_min, pgdi, ds, hand_min,
                                            hand_w, hand_idx, out);
}